// Round 13
// baseline (5825.413 us; speedup 1.0000x reference)
//
#include <hip/hip_runtime.h>
#include <hip/hip_fp16.h>
#include <stdint.h>

typedef _Float16 f16;
typedef _Float16 f16x8 __attribute__((ext_vector_type(8)));
typedef _Float16 f16x4 __attribute__((ext_vector_type(4)));
typedef float f32x4 __attribute__((ext_vector_type(4)));
typedef short s16x8 __attribute__((ext_vector_type(8)));          // 8 bf16
typedef unsigned short u16x8 __attribute__((ext_vector_type(8)));
typedef unsigned short u16x4 __attribute__((ext_vector_type(4)));

#define DEV __device__ __forceinline__

DEV void gload_lds16(const void* g, void* l) {
    __builtin_amdgcn_global_load_lds(
        (const __attribute__((address_space(1))) void*)g,
        (__attribute__((address_space(3))) void*)l, 16, 0, 0);
}

DEV unsigned short f32_to_bf16(float x) {
    union { float f; unsigned int u; } c; c.f = x;
    unsigned int r = (c.u + 0x7FFFu + ((c.u >> 16) & 1u)) >> 16;
    return (unsigned short)r;
}

// XCD panel-grouped swizzle (m-panels pinned per XCD): used by ctx/final.
DEV void swz_map(int bid, int nx, int ny, int& bm, int& bn) {
    const int xcd = bid & 7;
    const int j = bid >> 3;
    const int py = ny >> 3;
    bm = xcd * py + j / nx;
    bn = j % nx;
}

// XCD n-grouped swizzle (n-tiles pinned per XCD, m fastest): for score.
// Per-XCD B working set = (nx/8) n-tiles pinned in L2; A panels stream
// through L3 in the same order on all XCDs. Requires nx % 8 == 0.
DEV void swz_map_n(int bid, int nx, int& bm, int& bn) {
    const int xcd = bid & 7;
    const int j = bid >> 3;
    const int px = nx >> 3;
    bn = xcd * px + (j % px);
    bm = j / px;
}

// Shared score epilogue: e = exp(acc-150) -> bf16 store + fused row-sum
// (shfl over fr-group + one atomicAdd per row per wave).
DEV void score_epilogue(f32x4 (&acc)[4][4], size_t m0, size_t n0,
                        int wrow, int wcol, int lane, int ldc,
                        unsigned short* __restrict__ Sp,
                        float* __restrict__ rsum)
{
    const int fr = lane & 15;
    const int fq = lane >> 4;
#pragma unroll
    for (int mi = 0; mi < 4; ++mi)
#pragma unroll
        for (int r = 0; r < 4; ++r) {
            const size_t row = m0 + wrow + mi * 16 + fq * 4 + r;
            float rowacc = 0.f;
#pragma unroll
            for (int ni = 0; ni < 4; ++ni) {
                const size_t col = n0 + wcol + ni * 16 + fr;
                const float e = __expf(acc[mi][ni][r] - 150.f);
                Sp[row * (size_t)ldc + col] = f32_to_bf16(e);
                rowacc += e;
            }
#pragma unroll
            for (int m = 1; m < 16; m <<= 1) rowacc += __shfl_xor(rowacc, m);
            if (fr == 0) atomicAdd(&rsum[row], rowacc);
        }
}

// ---------------------------------------------------------------------------
// Score GEMM (4-operand fp16, 256x128 tile, 8 waves/512 thr, XCD n-grouped
// 1-D grid = nx * M/256): S' = bf16(exp((Ah+Al)@(Bh+Bl)^T - 150)), K=1024,
// drop lo*lo. Single-buffered 2-barrier loop; TLP via 3 blocks/CU
// (LDS 48KB x3 = 144 <= 160; VGPR 64 <= 85 at 6 waves/EU).
// Fused row-sum atomics. ldc = nx*128.
// ---------------------------------------------------------------------------
__global__ __launch_bounds__(512, 6) void gemm_score_4op(
    const f16* __restrict__ Ahi, const f16* __restrict__ Alo,
    const f16* __restrict__ Bhi, const f16* __restrict__ Blo,
    int nx, unsigned short* __restrict__ Sp, float* __restrict__ rsum)
{
    __shared__ alignas(16) f16 As_hi[256 * 32];
    __shared__ alignas(16) f16 As_lo[256 * 32];
    __shared__ alignas(16) f16 Bs_hi[128 * 32];
    __shared__ alignas(16) f16 Bs_lo[128 * 32];
    const int t = threadIdx.x;
    const int lane = t & 63;
    const int w = t >> 6;                 // 0..7
    int bm, bn;
    swz_map_n(blockIdx.x, nx, bm, bn);
    const size_t m0 = (size_t)bm * 256;
    const size_t n0 = (size_t)bn * 128;
    const int ldc = nx * 128;
    const int wrow = (w >> 1) * 64;       // 0,64,128,192
    const int wcol = (w & 1) * 64;        // 0,64
    const int fr = lane & 15;
    const int fk = (lane >> 4) << 3;

    // staging geometry (slot c covers row=c>>2, 16B col block (c&3)*8;
    // LDS dest is wave-uniform base + lane*16):
    const int cA0 = t, cA1 = 512 + t;     // A: 1024 slots (256 rows)
    const int rA0 = cA0 >> 2, qA0 = (cA0 & 3) << 3;
    const int rA1 = cA1 >> 2, qA1 = (cA1 & 3) << 3;
    const int loffA0 = (0 * 512 + w * 64) * 8;
    const int loffA1 = (1 * 512 + w * 64) * 8;
    const int rB = t >> 2, qB = (t & 3) << 3;   // B: 512 slots (128 rows)
    const int loffB = (w * 64) * 8;
    const size_t gA0 = (m0 + rA0) * 1024 + qA0;
    const size_t gA1 = (m0 + rA1) * 1024 + qA1;
    const size_t gB  = (n0 + rB) * 1024 + qB;

    f32x4 acc[4][4] = {};

    for (int k0 = 0; k0 < 1024; k0 += 32) {
        __syncthreads();
        gload_lds16(Ahi + gA0 + k0, &As_hi[loffA0]);
        gload_lds16(Ahi + gA1 + k0, &As_hi[loffA1]);
        gload_lds16(Alo + gA0 + k0, &As_lo[loffA0]);
        gload_lds16(Alo + gA1 + k0, &As_lo[loffA1]);
        gload_lds16(Bhi + gB + k0, &Bs_hi[loffB]);
        gload_lds16(Blo + gB + k0, &Bs_lo[loffB]);
        __syncthreads();
        f16x8 ah[4], al[4], bh[4], bl[4];
#pragma unroll
        for (int x = 0; x < 4; ++x) {
            const int ea = (wrow + x * 16 + fr) * 32 + fk;
            const int eb = (wcol + x * 16 + fr) * 32 + fk;
            ah[x] = *(const f16x8*)&As_hi[ea];
            al[x] = *(const f16x8*)&As_lo[ea];
            bh[x] = *(const f16x8*)&Bs_hi[eb];
            bl[x] = *(const f16x8*)&Bs_lo[eb];
        }
#pragma unroll
        for (int mi = 0; mi < 4; ++mi)
#pragma unroll
            for (int ni = 0; ni < 4; ++ni) {
                acc[mi][ni] = __builtin_amdgcn_mfma_f32_16x16x32_f16(ah[mi], bh[ni], acc[mi][ni], 0, 0, 0);
                acc[mi][ni] = __builtin_amdgcn_mfma_f32_16x16x32_f16(al[mi], bh[ni], acc[mi][ni], 0, 0, 0);
                acc[mi][ni] = __builtin_amdgcn_mfma_f32_16x16x32_f16(ah[mi], bl[ni], acc[mi][ni], 0, 0, 0);
            }
    }

    score_epilogue(acc, m0, n0, wrow, wcol, lane, ldc, Sp, rsum);
}

// ---------------------------------------------------------------------------
// Projection GEMM: P(hi,lo) = (A_f32 split) @ (B_f32 split)^T + bias, K=1024.
// ---------------------------------------------------------------------------
__global__ __launch_bounds__(256, 3) void gemm_proj(
    const float* __restrict__ A, const float* __restrict__ B,
    const float* __restrict__ bias, int ldc,
    f16* __restrict__ Phi, f16* __restrict__ Plo)
{
    __shared__ alignas(16) f16 As_hi[128 * 32];
    __shared__ alignas(16) f16 As_lo[128 * 32];
    __shared__ alignas(16) f16 Bs_hi[128 * 32];
    __shared__ alignas(16) f16 Bs_lo[128 * 32];
    const int t = threadIdx.x;
    const int lane = t & 63;
    const int w = t >> 6;
    const size_t m0 = (size_t)blockIdx.y * 128;
    const size_t n0 = (size_t)blockIdx.x * 128;
    const int wrow = (w >> 1) * 64;
    const int wcol = (w & 1) * 64;

    f32x4 acc[4][4] = {};

    for (int k0 = 0; k0 < 1024; k0 += 32) {
        __syncthreads();
#pragma unroll
        for (int p = 0; p < 4; ++p) {
            const int idx = p * 256 + t;
            const int row = idx >> 3;
            const int col4 = (idx & 7) << 2;
            const f32x4 va = *(const f32x4*)&A[(m0 + row) * 1024 + k0 + col4];
            const f32x4 vb = *(const f32x4*)&B[(n0 + row) * 1024 + k0 + col4];
            f16x4 ha, la, hb, lb;
#pragma unroll
            for (int j = 0; j < 4; ++j) {
                ha[j] = (f16)va[j];
                la[j] = (f16)(va[j] - (float)ha[j]);
                hb[j] = (f16)vb[j];
                lb[j] = (f16)(vb[j] - (float)hb[j]);
            }
            *(f16x4*)&As_hi[idx * 4] = ha;
            *(f16x4*)&As_lo[idx * 4] = la;
            *(f16x4*)&Bs_hi[idx * 4] = hb;
            *(f16x4*)&Bs_lo[idx * 4] = lb;
        }
        __syncthreads();
        const int fr = lane & 15;
        const int fk = (lane >> 4) << 3;
        f16x8 ah[4], al[4], bh[4], bl[4];
#pragma unroll
        for (int x = 0; x < 4; ++x) {
            ah[x] = *(const f16x8*)&As_hi[(wrow + x * 16 + fr) * 32 + fk];
            al[x] = *(const f16x8*)&As_lo[(wrow + x * 16 + fr) * 32 + fk];
            bh[x] = *(const f16x8*)&Bs_hi[(wcol + x * 16 + fr) * 32 + fk];
            bl[x] = *(const f16x8*)&Bs_lo[(wcol + x * 16 + fr) * 32 + fk];
        }
#pragma unroll
        for (int mi = 0; mi < 4; ++mi)
#pragma unroll
            for (int ni = 0; ni < 4; ++ni) {
                acc[mi][ni] = __builtin_amdgcn_mfma_f32_16x16x32_f16(ah[mi], bh[ni], acc[mi][ni], 0, 0, 0);
                acc[mi][ni] = __builtin_amdgcn_mfma_f32_16x16x32_f16(al[mi], bh[ni], acc[mi][ni], 0, 0, 0);
                acc[mi][ni] = __builtin_amdgcn_mfma_f32_16x16x32_f16(ah[mi], bl[ni], acc[mi][ni], 0, 0, 0);
            }
    }

    const int fr = lane & 15;
    const int fq = lane >> 4;
#pragma unroll
    for (int mi = 0; mi < 4; ++mi)
#pragma unroll
        for (int ni = 0; ni < 4; ++ni)
#pragma unroll
            for (int r = 0; r < 4; ++r) {
                const size_t row = m0 + wrow + mi * 16 + fq * 4 + r;
                const size_t col = n0 + wcol + ni * 16 + fr;
                float v = acc[mi][ni][r] + bias[col];
                const f16 h = (f16)v;
                Phi[row * (size_t)ldc + col] = h;
                Plo[row * (size_t)ldc + col] = (f16)(v - (float)h);
            }
}

// ---------------------------------------------------------------------------
// bf16 ctx GEMM with split-K x2: grid = 1024 (2 K-halves x 512 XCD-swz).
// Partial(fp16) = (A[:, kh*K2..) @ B[:, same)^T) * inv_sum[row].
// 5 blocks/CU (LDS 32KB x5 = 160; VGPR 60 <= 102).
// ---------------------------------------------------------------------------
__global__ __launch_bounds__(256, 5) void gemm_ctx_sk(
    const unsigned short* __restrict__ A, const unsigned short* __restrict__ B,
    const float* __restrict__ isum, int ldk, int K2,
    f16* __restrict__ P0, f16* __restrict__ P1)
{
    __shared__ alignas(16) unsigned short LA[2][128 * 32];
    __shared__ alignas(16) unsigned short LB[2][128 * 32];
    const int t = threadIdx.x;
    const int lane = t & 63;
    const int w = t >> 6;
    const int kh = blockIdx.x >> 9;
    int bm, bn;
    swz_map(blockIdx.x & 511, 8, 64, bm, bn);
    const size_t m0 = (size_t)bm * 128;
    const size_t n0 = (size_t)bn * 128;
    const size_t koff = (size_t)kh * K2;
    const int wrow = (w >> 1) * 64;
    const int wcol = (w & 1) * 64;
    const int fr = lane & 15;
    const int bslot = lane >> 4;
    f16* __restrict__ P = kh ? P1 : P0;

    const int s0 = t, s1 = 256 + t;
    const int r0 = s0 >> 2, c0 = s0 & 3;
    const int r1 = s1 >> 2, c1 = s1 & 3;
    const size_t ga0 = (m0 + r0) * (size_t)ldk + koff + ((c0 ^ (r0 & 3)) << 3);
    const size_t ga1 = (m0 + r1) * (size_t)ldk + koff + ((c1 ^ (r1 & 3)) << 3);
    const size_t gb0 = (n0 + r0) * (size_t)ldk + koff + ((c0 ^ (r0 & 3)) << 3);
    const size_t gb1 = (n0 + r1) * (size_t)ldk + koff + ((c1 ^ (r1 & 3)) << 3);

    f32x4 acc[4][4] = {};

    auto stage = [&](int kt, int b) {
        const int k0 = kt << 5;
        gload_lds16(A + ga0 + k0, &LA[b][(size_t)s0 * 8]);
        gload_lds16(A + ga1 + k0, &LA[b][(size_t)s1 * 8]);
        gload_lds16(B + gb0 + k0, &LB[b][(size_t)s0 * 8]);
        gload_lds16(B + gb1 + k0, &LB[b][(size_t)s1 * 8]);
    };

    auto compute = [&](int b) {
        s16x8 a[4], bb[4];
#pragma unroll
        for (int x = 0; x < 4; ++x) {
            const int ra = wrow + x * 16 + fr;
            const int rb = wcol + x * 16 + fr;
            a[x]  = *(const s16x8*)&LA[b][ra * 32 + ((bslot ^ (ra & 3)) << 3)];
            bb[x] = *(const s16x8*)&LB[b][rb * 32 + ((bslot ^ (rb & 3)) << 3)];
        }
#pragma unroll
        for (int mi = 0; mi < 4; ++mi)
#pragma unroll
            for (int ni = 0; ni < 4; ++ni)
                acc[mi][ni] = __builtin_amdgcn_mfma_f32_16x16x32_bf16(a[mi], bb[ni], acc[mi][ni], 0, 0, 0);
    };

    const int NT = K2 >> 5;
    stage(0, 0);
#pragma unroll 1
    for (int kt = 0; kt < NT; kt += 2) {
        __syncthreads();
        if (kt + 1 < NT) stage(kt + 1, 1);
        __builtin_amdgcn_s_setprio(1);
        compute(0);
        __builtin_amdgcn_s_setprio(0);
        __syncthreads();
        if (kt + 2 < NT) stage(kt + 2, 0);
        __builtin_amdgcn_s_setprio(1);
        compute(1);
        __builtin_amdgcn_s_setprio(0);
    }

    const int fq = lane >> 4;
#pragma unroll
    for (int mi = 0; mi < 4; ++mi)
#pragma unroll
        for (int ni = 0; ni < 4; ++ni)
#pragma unroll
            for (int r = 0; r < 4; ++r) {
                const size_t row = m0 + wrow + mi * 16 + fq * 4 + r;
                const size_t col = n0 + wcol + ni * 16 + fr;
                P[row * 1024 + col] = (f16)(acc[mi][ni][r] * isum[row]);
            }
}

// ---------------------------------------------------------------------------
// Final GEMM, split-K x2: fp16 partial of cat @ Wlin^T (no bias/tanh).
// ---------------------------------------------------------------------------
__global__ __launch_bounds__(256, 3) void gemm_final_sk(
    const float* __restrict__ A0, const f16* __restrict__ A1,
    const f16* __restrict__ A2, const f16* __restrict__ B,
    f16* __restrict__ P0, f16* __restrict__ P1)
{
    __shared__ alignas(16) f16 As[128 * 32];
    __shared__ alignas(16) f16 Bs[128 * 32];
    const int t = threadIdx.x;
    const int lane = t & 63;
    const int w = t >> 6;
    const int kh = blockIdx.x >> 9;
    int bm, bn;
    swz_map(blockIdx.x & 511, 8, 64, bm, bn);
    const size_t m0 = (size_t)bm * 128;
    const size_t n0 = (size_t)bn * 128;
    const int wrow = (w >> 1) * 64;
    const int wcol = (w & 1) * 64;
    const int kBeg = kh * 1536;
    f16* __restrict__ P = kh ? P1 : P0;

    f32x4 acc[4][4] = {};

    for (int k0 = kBeg; k0 < kBeg + 1536; k0 += 32) {
        const int kl = k0 & 1023;
        __syncthreads();
        if (k0 < 1024) {
#pragma unroll
            for (int p = 0; p < 4; ++p) {
                const int idx = p * 256 + t;
                const int row = idx >> 3;
                const int col4 = (idx & 7) << 2;
                const f32x4 v = *(const f32x4*)&A0[(m0 + row) * 1024 + kl + col4];
                f16x4 h;
#pragma unroll
                for (int j = 0; j < 4; ++j) h[j] = (f16)v[j];
                *(f16x4*)&As[idx * 4] = h;
            }
        } else {
            const f16* Aseg = (k0 < 2048) ? A1 : A2;
#pragma unroll
            for (int i = 0; i < 2; ++i) {
                const int c = i * 256 + t;
                const int row = c >> 2;
                const int col = (c & 3) << 3;
                const int loff = (i * 256 + w * 64) * 8;
                gload_lds16(Aseg + (m0 + row) * (size_t)1024 + kl + col, &As[loff]);
            }
        }
#pragma unroll
        for (int i = 0; i < 2; ++i) {
            const int c = i * 256 + t;
            const int row = c >> 2;
            const int col = (c & 3) << 3;
            const int loff = (i * 256 + w * 64) * 8;
            gload_lds16(B + (n0 + row) * (size_t)3072 + k0 + col, &Bs[loff]);
        }
        __syncthreads();
        const int fr = lane & 15;
        const int fk = (lane >> 4) << 3;
        f16x8 a[4], b[4];
#pragma unroll
        for (int x = 0; x < 4; ++x) {
            a[x] = *(const f16x8*)&As[(wrow + x * 16 + fr) * 32 + fk];
            b[x] = *(const f16x8*)&Bs[(wcol + x * 16 + fr) * 32 + fk];
        }
#pragma unroll
        for (int mi = 0; mi < 4; ++mi)
#pragma unroll
            for (int ni = 0; ni < 4; ++ni)
                acc[mi][ni] = __builtin_amdgcn_mfma_f32_16x16x32_f16(a[mi], b[ni], acc[mi][ni], 0, 0, 0);
    }

    const int fr = lane & 15;
    const int fq = lane >> 4;
#pragma unroll
    for (int mi = 0; mi < 4; ++mi)
#pragma unroll
        for (int ni = 0; ni < 4; ++ni)
#pragma unroll
            for (int r = 0; r < 4; ++r) {
                const size_t row = m0 + wrow + mi * 16 + fq * 4 + r;
                const size_t col = n0 + wcol + ni * 16 + fr;
                P[row * 1024 + col] = (f16)acc[mi][ni][r];
            }
}

// ---------------------------------------------------------------------------
// Reduce / small kernels
// ---------------------------------------------------------------------------
__global__ __launch_bounds__(256) void reduce_add_f16(
    const f16* __restrict__ p0, const f16* __restrict__ p1,
    f16* __restrict__ out, int n8)
{
    for (int i = blockIdx.x * 256 + threadIdx.x; i < n8; i += gridDim.x * 256) {
        const f16x8 a = *(const f16x8*)&p0[(size_t)i * 8];
        const f16x8 b = *(const f16x8*)&p1[(size_t)i * 8];
        f16x8 o;
#pragma unroll
        for (int j = 0; j < 8; ++j) o[j] = (f16)((float)a[j] + (float)b[j]);
        *(f16x8*)&out[(size_t)i * 8] = o;
    }
}

__global__ __launch_bounds__(256) void reduce_tanh_f32(
    const f16* __restrict__ p0, const f16* __restrict__ p1,
    const float* __restrict__ bias, float* __restrict__ out, int n4)
{
    for (int i = blockIdx.x * 256 + threadIdx.x; i < n4; i += gridDim.x * 256) {
        const size_t e = (size_t)i * 4;
        const f16x4 a = *(const f16x4*)&p0[e];
        const f16x4 b = *(const f16x4*)&p1[e];
        f32x4 o;
#pragma unroll
        for (int j = 0; j < 4; ++j)
            o[j] = tanhf((float)a[j] + (float)b[j] + bias[(e + j) & 1023]);
        *(f32x4*)&out[e] = o;
    }
}

__global__ __launch_bounds__(256) void zero_f32(float* __restrict__ p, int n) {
    const int i = blockIdx.x * 256 + threadIdx.x;
    if (i < n) p[i] = 0.f;
}

__global__ __launch_bounds__(256) void inv_f32(float* __restrict__ p, int n) {
    const int i = blockIdx.x * 256 + threadIdx.x;
    if (i < n) p[i] = 1.f / p[i];
}

__global__ __launch_bounds__(256) void split_f32_f16(
    const float* __restrict__ X, f16* __restrict__ hi, f16* __restrict__ lo)
{
    const size_t i = ((size_t)blockIdx.x * 256 + threadIdx.x) * 4;
    const f32x4 v = *(const f32x4*)&X[i];
    f16x4 h, l;
#pragma unroll
    for (int j = 0; j < 4; ++j) {
        h[j] = (f16)v[j];
        l[j] = (f16)(v[j] - (float)h[j]);
    }
    *(f16x4*)&hi[i] = h;
    *(f16x4*)&lo[i] = l;
}

// ---------------------------------------------------------------------------
// Transpose X[N,H] f32 -> Xt[H,N] bf16 (64x64 tiles via LDS)
// ---------------------------------------------------------------------------
__global__ __launch_bounds__(256) void transpose_f32_to_bf16(
    const float* __restrict__ X, unsigned short* __restrict__ Xt, int N, int H)
{
    __shared__ float tile[64][65];
    const int n0 = blockIdx.x * 64;
    const int h0 = blockIdx.y * 64;
    const int tx = threadIdx.x & 15;
    const int ty = threadIdx.x >> 4;
#pragma unroll
    for (int i = 0; i < 4; ++i) {
        const int r = ty + i * 16;
        const f32x4 vv = *(const f32x4*)&X[(size_t)(n0 + r) * H + h0 + tx * 4];
        tile[r][tx * 4 + 0] = vv[0];
        tile[r][tx * 4 + 1] = vv[1];
        tile[r][tx * 4 + 2] = vv[2];
        tile[r][tx * 4 + 3] = vv[3];
    }
    __syncthreads();
#pragma unroll
    for (int i = 0; i < 4; ++i) {
        const int hh = ty + i * 16;
        u16x4 o;
        o[0] = f32_to_bf16(tile[tx * 4 + 0][hh]);
        o[1] = f32_to_bf16(tile[tx * 4 + 1][hh]);
        o[2] = f32_to_bf16(tile[tx * 4 + 2][hh]);
        o[3] = f32_to_bf16(tile[tx * 4 + 3][hh]);
        *(u16x4*)&Xt[(size_t)(h0 + hh) * N + n0 + tx * 4] = o;
    }
}

__global__ __launch_bounds__(256) void conv_f32_f16(
    const float* __restrict__ X, f16* __restrict__ Y)
{
    const size_t i = ((size_t)blockIdx.x * 256 + threadIdx.x) * 4;
    const f32x4 v = *(const f32x4*)&X[i];
    f16x4 h;
#pragma unroll
    for (int j = 0; j < 4; ++j) h[j] = (f16)v[j];
    *(f16x4*)&Y[i] = h;
}

// ---------------------------------------------------------------------------
extern "C" void kernel_launch(void* const* d_in, const int* in_sizes, int n_in,
                              void* d_out, int out_size, void* d_ws, size_t ws_size,
                              hipStream_t stream)
{
    (void)in_sizes; (void)n_in; (void)out_size;
    constexpr int Ns = 8192, Ne = 4096, M = 8192, H = 1024, K3 = 3072, AO = 1024;

    const float* Xss  = (const float*)d_in[0];
    const float* Xes  = (const float*)d_in[1];
    const float* Att  = (const float*)d_in[2];
    const float* Wss  = (const float*)d_in[3];
    const float* bss  = (const float*)d_in[4];
    const float* Wes  = (const float*)d_in[5];
    const float* bes  = (const float*)d_in[6];
    const float* Wlin = (const float*)d_in[7];
    const float* blin = (const float*)d_in[8];
    float* Out = (float*)d_out;

    // ---- workspace layout (~249.7 MB) ----
    char* base = (char*)d_ws;
    size_t off = 0;
    auto carve = [&](size_t bytes) {
        char* r = base + off;
        off = (off + bytes + 255) & ~(size_t)255;
        return r;
    };

    f16* Wl16            = (f16*)carve((size_t)AO * K3 * 2);            //   6.3 MB
    unsigned short* Vtss = (unsigned short*)carve((size_t)H * Ns * 2);  //  16.8 MB
    unsigned short* Vtes = (unsigned short*)carve((size_t)H * Ne * 2);  //   8.4 MB
    char* PesRg          = carve((size_t)2 * Ne * H * 2);               //  16.8 MB (Pes hi/lo -> Att_hi)
    char* PssRg          = carve((size_t)2 * Ns * H * 2);               //  33.6 MB (Pss hi/lo -> ctx-ss partials)
    char* E              = carve((size_t)M * Ns * 2);                   // 134.2 MB
    char* CtxssRg        = carve((size_t)M * H * 2);                    //  16.8 MB (Att_lo -> Ctxss)
    f16* Ctxes           = (f16*)carve((size_t)M * H * 2);              //  16.8 MB
    float* sum_ss        = (float*)carve((size_t)M * 4);
    float* sum_es        = (float*)carve((size_t)M * 4);
    if (off > ws_size) return;  // ws too small: fail loudly

    // Aliases into E: [0,67.1M) Ses | [67.1,83.9M) AhE | [83.9,100.7M) AlE
    //                 | [100.7,134.2M) es ctx partials. Then all of E = Sss,
    //                 then E = final partials. Liveness per launch order.
    f16* Pes_hi = (f16*)PesRg;
    f16* Pes_lo = Pes_hi + (size_t)Ne * H;
    f16* Att_hi = (f16*)PesRg;                         // after score-es
    f16* Att_lo = (f16*)CtxssRg;                       // until score-ss done
    f16* Pss_hi = (f16*)PssRg;
    f16* Pss_lo = Pss_hi + (size_t)Ns * H;
    unsigned short* Ses = (unsigned short*)E;          // [M, Ne]
    unsigned short* Sss = (unsigned short*)E;          // [M, Ns]
    f16* AhE   = (f16*)(E + (size_t)M * Ne * 2);       // es-phase Att hi
    f16* AlE   = AhE + (size_t)M * H;                  // es-phase Att lo
    f16* esP0  = (f16*)(E + (size_t)M * Ne * 2 + (size_t)2 * M * H * 2);
    f16* esP1  = esP0 + (size_t)M * H;                 // ends exactly at E end
    f16* ssP0  = (f16*)PssRg;                          // ss ctx partials (Pss dead)
    f16* ssP1  = ssP0 + (size_t)M * H;
    f16* Ctxss = (f16*)CtxssRg;
    f16* fnP0  = (f16*)E;                              // final partials (E dead)
    f16* fnP1  = fnP0 + (size_t)M * AO;

    const int n8 = (M * H) / 8;
    const int n4 = (M * AO) / 4;

    // ---- stage 0: conversions + sum init ----
    conv_f32_f16<<<(AO * K3) / 1024, 256, 0, stream>>>(Wlin, Wl16);
    transpose_f32_to_bf16<<<dim3(Ns / 64, H / 64), 256, 0, stream>>>(Xss, Vtss, Ns, H);
    transpose_f32_to_bf16<<<dim3(Ne / 64, H / 64), 256, 0, stream>>>(Xes, Vtes, Ne, H);
    zero_f32<<<(2 * M) / 256, 256, 0, stream>>>(sum_ss, 2 * M);  // sum_ss+sum_es contiguous

    // ---- stage 1: projections ----
    gemm_proj<<<dim3(H / 128, Ns / 128), 256, 0, stream>>>(Xss, Wss, bss, H, Pss_hi, Pss_lo);
    gemm_proj<<<dim3(H / 128, Ne / 128), 256, 0, stream>>>(Xes, Wes, bes, H, Pes_hi, Pes_lo);

    // ---- es phase: split Att into E tail -> score(4op, n-swz, 256x128) -> ctx ----
    split_f32_f16<<<(M * H) / 1024, 256, 0, stream>>>(Att, AhE, AlE);
    gemm_score_4op<<<32 * (M / 256), 512, 0, stream>>>(
        AhE, AlE, Pes_hi, Pes_lo, 32, Ses, sum_es);
    // re-split Att into persistent homes (Pes dead now; CtxssRg unwritten)
    split_f32_f16<<<(M * H) / 1024, 256, 0, stream>>>(Att, Att_hi, Att_lo);
    inv_f32<<<M / 256, 256, 0, stream>>>(sum_es, M);
    gemm_ctx_sk<<<1024, 256, 0, stream>>>(Ses, Vtes, sum_es, Ne, Ne / 2, esP0, esP1);
    reduce_add_f16<<<1024, 256, 0, stream>>>(esP0, esP1, Ctxes, n8);

    // ---- ss phase: score(4op, n-swz, 256x128) -> ctx ----
    gemm_score_4op<<<64 * (M / 256), 512, 0, stream>>>(
        Att_hi, Att_lo, Pss_hi, Pss_lo, 64, Sss, sum_ss);
    inv_f32<<<M / 256, 256, 0, stream>>>(sum_ss, M);
    gemm_ctx_sk<<<1024, 256, 0, stream>>>(Sss, Vtss, sum_ss, Ns, Ns / 2, ssP0, ssP1);
    reduce_add_f16<<<1024, 256, 0, stream>>>(ssP0, ssP1, Ctxss, n8);

    // ---- stage 3: out = tanh([att, ctx_ss, ctx_es] @ Wlin^T + b) ----
    gemm_final_sk<<<1024, 256, 0, stream>>>(Att, Ctxss, Ctxes, Wl16, fnP0, fnP1);
    reduce_tanh_f32<<<1024, 256, 0, stream>>>(fnP0, fnP1, blin, Out, n4);
}

// Round 14
// 1315.196 us; speedup vs baseline: 4.4293x; 4.4293x over previous
//
#include <hip/hip_runtime.h>
#include <hip/hip_fp16.h>
#include <stdint.h>

typedef _Float16 f16;
typedef _Float16 f16x8 __attribute__((ext_vector_type(8)));
typedef _Float16 f16x4 __attribute__((ext_vector_type(4)));
typedef float f32x4 __attribute__((ext_vector_type(4)));
typedef short s16x8 __attribute__((ext_vector_type(8)));          // 8 bf16
typedef unsigned short u16x8 __attribute__((ext_vector_type(8)));
typedef unsigned short u16x4 __attribute__((ext_vector_type(4)));

#define DEV __device__ __forceinline__

DEV void gload_lds16(const void* g, void* l) {
    __builtin_amdgcn_global_load_lds(
        (const __attribute__((address_space(1))) void*)g,
        (__attribute__((address_space(3))) void*)l, 16, 0, 0);
}

DEV unsigned short f32_to_bf16(float x) {
    union { float f; unsigned int u; } c; c.f = x;
    unsigned int r = (c.u + 0x7FFFu + ((c.u >> 16) & 1u)) >> 16;
    return (unsigned short)r;
}

// XCD panel-grouped swizzle (m-panels pinned per XCD): used by ctx/final.
DEV void swz_map(int bid, int nx, int ny, int& bm, int& bn) {
    const int xcd = bid & 7;
    const int j = bid >> 3;
    const int py = ny >> 3;
    bm = xcd * py + j / nx;
    bn = j % nx;
}

// XCD n-grouped swizzle (n-tiles pinned per XCD, m fastest): for score.
DEV void swz_map_n(int bid, int nx, int& bm, int& bn) {
    const int xcd = bid & 7;
    const int j = bid >> 3;
    const int px = nx >> 3;
    bn = xcd * px + (j % px);
    bm = j / px;
}

// Shared score epilogue: e = exp(acc-150) -> bf16 store + fused row-sum
// (shfl over fr-group + one atomicAdd per row per wave).
DEV void score_epilogue(f32x4 (&acc)[4][4], size_t m0, size_t n0,
                        int wrow, int wcol, int lane, int ldc,
                        unsigned short* __restrict__ Sp,
                        float* __restrict__ rsum)
{
    const int fr = lane & 15;
    const int fq = lane >> 4;
#pragma unroll
    for (int mi = 0; mi < 4; ++mi)
#pragma unroll
        for (int r = 0; r < 4; ++r) {
            const size_t row = m0 + wrow + mi * 16 + fq * 4 + r;
            float rowacc = 0.f;
#pragma unroll
            for (int ni = 0; ni < 4; ++ni) {
                const size_t col = n0 + wcol + ni * 16 + fr;
                const float e = __expf(acc[mi][ni][r] - 150.f);
                Sp[row * (size_t)ldc + col] = f32_to_bf16(e);
                rowacc += e;
            }
#pragma unroll
            for (int m = 1; m < 16; m <<= 1) rowacc += __shfl_xor(rowacc, m);
            if (fr == 0) atomicAdd(&rsum[row], rowacc);
        }
}

// ---------------------------------------------------------------------------
// Score GEMM (4-operand fp16, 256x128 tile, 8 waves/512 thr, XCD n-grouped
// 1-D grid = nx * M/256): S' = bf16(exp((Ah+Al)@(Bh+Bl)^T - 150)), K=1024,
// drop lo*lo. Single-buffered 2-barrier loop; 2 blocks/CU.
// NOTE: (512,6) forces VGPR<=85 -> accumulator spill to scratch (r13:
// 9.8GB scratch writes, 5.5x slowdown). (512,4) is the max safe occupancy.
// Fused row-sum atomics. ldc = nx*128.
// ---------------------------------------------------------------------------
__global__ __launch_bounds__(512, 4) void gemm_score_4op(
    const f16* __restrict__ Ahi, const f16* __restrict__ Alo,
    const f16* __restrict__ Bhi, const f16* __restrict__ Blo,
    int nx, unsigned short* __restrict__ Sp, float* __restrict__ rsum)
{
    __shared__ alignas(16) f16 As_hi[256 * 32];
    __shared__ alignas(16) f16 As_lo[256 * 32];
    __shared__ alignas(16) f16 Bs_hi[128 * 32];
    __shared__ alignas(16) f16 Bs_lo[128 * 32];
    const int t = threadIdx.x;
    const int lane = t & 63;
    const int w = t >> 6;                 // 0..7
    int bm, bn;
    swz_map_n(blockIdx.x, nx, bm, bn);
    const size_t m0 = (size_t)bm * 256;
    const size_t n0 = (size_t)bn * 128;
    const int ldc = nx * 128;
    const int wrow = (w >> 1) * 64;       // 0,64,128,192
    const int wcol = (w & 1) * 64;        // 0,64
    const int fr = lane & 15;
    const int fk = (lane >> 4) << 3;

    const int cA0 = t, cA1 = 512 + t;     // A: 1024 slots (256 rows)
    const int rA0 = cA0 >> 2, qA0 = (cA0 & 3) << 3;
    const int rA1 = cA1 >> 2, qA1 = (cA1 & 3) << 3;
    const int loffA0 = (0 * 512 + w * 64) * 8;
    const int loffA1 = (1 * 512 + w * 64) * 8;
    const int rB = t >> 2, qB = (t & 3) << 3;   // B: 512 slots (128 rows)
    const int loffB = (w * 64) * 8;
    const size_t gA0 = (m0 + rA0) * 1024 + qA0;
    const size_t gA1 = (m0 + rA1) * 1024 + qA1;
    const size_t gB  = (n0 + rB) * 1024 + qB;

    f32x4 acc[4][4] = {};

    for (int k0 = 0; k0 < 1024; k0 += 32) {
        __syncthreads();
        gload_lds16(Ahi + gA0 + k0, &As_hi[loffA0]);
        gload_lds16(Ahi + gA1 + k0, &As_hi[loffA1]);
        gload_lds16(Alo + gA0 + k0, &As_lo[loffA0]);
        gload_lds16(Alo + gA1 + k0, &As_lo[loffA1]);
        gload_lds16(Bhi + gB + k0, &Bs_hi[loffB]);
        gload_lds16(Blo + gB + k0, &Bs_lo[loffB]);
        __syncthreads();
        f16x8 ah[4], al[4], bh[4], bl[4];
#pragma unroll
        for (int x = 0; x < 4; ++x) {
            const int ea = (wrow + x * 16 + fr) * 32 + fk;
            const int eb = (wcol + x * 16 + fr) * 32 + fk;
            ah[x] = *(const f16x8*)&As_hi[ea];
            al[x] = *(const f16x8*)&As_lo[ea];
            bh[x] = *(const f16x8*)&Bs_hi[eb];
            bl[x] = *(const f16x8*)&Bs_lo[eb];
        }
#pragma unroll
        for (int mi = 0; mi < 4; ++mi)
#pragma unroll
            for (int ni = 0; ni < 4; ++ni) {
                acc[mi][ni] = __builtin_amdgcn_mfma_f32_16x16x32_f16(ah[mi], bh[ni], acc[mi][ni], 0, 0, 0);
                acc[mi][ni] = __builtin_amdgcn_mfma_f32_16x16x32_f16(al[mi], bh[ni], acc[mi][ni], 0, 0, 0);
                acc[mi][ni] = __builtin_amdgcn_mfma_f32_16x16x32_f16(ah[mi], bl[ni], acc[mi][ni], 0, 0, 0);
            }
    }

    score_epilogue(acc, m0, n0, wrow, wcol, lane, ldc, Sp, rsum);
}

// ---------------------------------------------------------------------------
// Projection GEMM: P(hi,lo) = (A_f32 split) @ (B_f32 split)^T + bias, K=1024.
// ---------------------------------------------------------------------------
__global__ __launch_bounds__(256, 3) void gemm_proj(
    const float* __restrict__ A, const float* __restrict__ B,
    const float* __restrict__ bias, int ldc,
    f16* __restrict__ Phi, f16* __restrict__ Plo)
{
    __shared__ alignas(16) f16 As_hi[128 * 32];
    __shared__ alignas(16) f16 As_lo[128 * 32];
    __shared__ alignas(16) f16 Bs_hi[128 * 32];
    __shared__ alignas(16) f16 Bs_lo[128 * 32];
    const int t = threadIdx.x;
    const int lane = t & 63;
    const int w = t >> 6;
    const size_t m0 = (size_t)blockIdx.y * 128;
    const size_t n0 = (size_t)blockIdx.x * 128;
    const int wrow = (w >> 1) * 64;
    const int wcol = (w & 1) * 64;

    f32x4 acc[4][4] = {};

    for (int k0 = 0; k0 < 1024; k0 += 32) {
        __syncthreads();
#pragma unroll
        for (int p = 0; p < 4; ++p) {
            const int idx = p * 256 + t;
            const int row = idx >> 3;
            const int col4 = (idx & 7) << 2;
            const f32x4 va = *(const f32x4*)&A[(m0 + row) * 1024 + k0 + col4];
            const f32x4 vb = *(const f32x4*)&B[(n0 + row) * 1024 + k0 + col4];
            f16x4 ha, la, hb, lb;
#pragma unroll
            for (int j = 0; j < 4; ++j) {
                ha[j] = (f16)va[j];
                la[j] = (f16)(va[j] - (float)ha[j]);
                hb[j] = (f16)vb[j];
                lb[j] = (f16)(vb[j] - (float)hb[j]);
            }
            *(f16x4*)&As_hi[idx * 4] = ha;
            *(f16x4*)&As_lo[idx * 4] = la;
            *(f16x4*)&Bs_hi[idx * 4] = hb;
            *(f16x4*)&Bs_lo[idx * 4] = lb;
        }
        __syncthreads();
        const int fr = lane & 15;
        const int fk = (lane >> 4) << 3;
        f16x8 ah[4], al[4], bh[4], bl[4];
#pragma unroll
        for (int x = 0; x < 4; ++x) {
            ah[x] = *(const f16x8*)&As_hi[(wrow + x * 16 + fr) * 32 + fk];
            al[x] = *(const f16x8*)&As_lo[(wrow + x * 16 + fr) * 32 + fk];
            bh[x] = *(const f16x8*)&Bs_hi[(wcol + x * 16 + fr) * 32 + fk];
            bl[x] = *(const f16x8*)&Bs_lo[(wcol + x * 16 + fr) * 32 + fk];
        }
#pragma unroll
        for (int mi = 0; mi < 4; ++mi)
#pragma unroll
            for (int ni = 0; ni < 4; ++ni) {
                acc[mi][ni] = __builtin_amdgcn_mfma_f32_16x16x32_f16(ah[mi], bh[ni], acc[mi][ni], 0, 0, 0);
                acc[mi][ni] = __builtin_amdgcn_mfma_f32_16x16x32_f16(al[mi], bh[ni], acc[mi][ni], 0, 0, 0);
                acc[mi][ni] = __builtin_amdgcn_mfma_f32_16x16x32_f16(ah[mi], bl[ni], acc[mi][ni], 0, 0, 0);
            }
    }

    const int fr = lane & 15;
    const int fq = lane >> 4;
#pragma unroll
    for (int mi = 0; mi < 4; ++mi)
#pragma unroll
        for (int ni = 0; ni < 4; ++ni)
#pragma unroll
            for (int r = 0; r < 4; ++r) {
                const size_t row = m0 + wrow + mi * 16 + fq * 4 + r;
                const size_t col = n0 + wcol + ni * 16 + fr;
                float v = acc[mi][ni][r] + bias[col];
                const f16 h = (f16)v;
                Phi[row * (size_t)ldc + col] = h;
                Plo[row * (size_t)ldc + col] = (f16)(v - (float)h);
            }
}

// ---------------------------------------------------------------------------
// bf16 ctx GEMM with split-K x2: grid = 1024 (2 K-halves x 512 XCD-swz).
// Partial(fp16) = (A[:, kh*K2..) @ B[:, same)^T) * inv_sum[row].
// 5 blocks/CU (LDS 32KB x5 = 160; VGPR 60 <= 102).
// ---------------------------------------------------------------------------
__global__ __launch_bounds__(256, 5) void gemm_ctx_sk(
    const unsigned short* __restrict__ A, const unsigned short* __restrict__ B,
    const float* __restrict__ isum, int ldk, int K2,
    f16* __restrict__ P0, f16* __restrict__ P1)
{
    __shared__ alignas(16) unsigned short LA[2][128 * 32];
    __shared__ alignas(16) unsigned short LB[2][128 * 32];
    const int t = threadIdx.x;
    const int lane = t & 63;
    const int w = t >> 6;
    const int kh = blockIdx.x >> 9;
    int bm, bn;
    swz_map(blockIdx.x & 511, 8, 64, bm, bn);
    const size_t m0 = (size_t)bm * 128;
    const size_t n0 = (size_t)bn * 128;
    const size_t koff = (size_t)kh * K2;
    const int wrow = (w >> 1) * 64;
    const int wcol = (w & 1) * 64;
    const int fr = lane & 15;
    const int bslot = lane >> 4;
    f16* __restrict__ P = kh ? P1 : P0;

    const int s0 = t, s1 = 256 + t;
    const int r0 = s0 >> 2, c0 = s0 & 3;
    const int r1 = s1 >> 2, c1 = s1 & 3;
    const size_t ga0 = (m0 + r0) * (size_t)ldk + koff + ((c0 ^ (r0 & 3)) << 3);
    const size_t ga1 = (m0 + r1) * (size_t)ldk + koff + ((c1 ^ (r1 & 3)) << 3);
    const size_t gb0 = (n0 + r0) * (size_t)ldk + koff + ((c0 ^ (r0 & 3)) << 3);
    const size_t gb1 = (n0 + r1) * (size_t)ldk + koff + ((c1 ^ (r1 & 3)) << 3);

    f32x4 acc[4][4] = {};

    auto stage = [&](int kt, int b) {
        const int k0 = kt << 5;
        gload_lds16(A + ga0 + k0, &LA[b][(size_t)s0 * 8]);
        gload_lds16(A + ga1 + k0, &LA[b][(size_t)s1 * 8]);
        gload_lds16(B + gb0 + k0, &LB[b][(size_t)s0 * 8]);
        gload_lds16(B + gb1 + k0, &LB[b][(size_t)s1 * 8]);
    };

    auto compute = [&](int b) {
        s16x8 a[4], bb[4];
#pragma unroll
        for (int x = 0; x < 4; ++x) {
            const int ra = wrow + x * 16 + fr;
            const int rb = wcol + x * 16 + fr;
            a[x]  = *(const s16x8*)&LA[b][ra * 32 + ((bslot ^ (ra & 3)) << 3)];
            bb[x] = *(const s16x8*)&LB[b][rb * 32 + ((bslot ^ (rb & 3)) << 3)];
        }
#pragma unroll
        for (int mi = 0; mi < 4; ++mi)
#pragma unroll
            for (int ni = 0; ni < 4; ++ni)
                acc[mi][ni] = __builtin_amdgcn_mfma_f32_16x16x32_bf16(a[mi], bb[ni], acc[mi][ni], 0, 0, 0);
    };

    const int NT = K2 >> 5;
    stage(0, 0);
#pragma unroll 1
    for (int kt = 0; kt < NT; kt += 2) {
        __syncthreads();
        if (kt + 1 < NT) stage(kt + 1, 1);
        __builtin_amdgcn_s_setprio(1);
        compute(0);
        __builtin_amdgcn_s_setprio(0);
        __syncthreads();
        if (kt + 2 < NT) stage(kt + 2, 0);
        __builtin_amdgcn_s_setprio(1);
        compute(1);
        __builtin_amdgcn_s_setprio(0);
    }

    const int fq = lane >> 4;
#pragma unroll
    for (int mi = 0; mi < 4; ++mi)
#pragma unroll
        for (int ni = 0; ni < 4; ++ni)
#pragma unroll
            for (int r = 0; r < 4; ++r) {
                const size_t row = m0 + wrow + mi * 16 + fq * 4 + r;
                const size_t col = n0 + wcol + ni * 16 + fr;
                P[row * 1024 + col] = (f16)(acc[mi][ni][r] * isum[row]);
            }
}

// ---------------------------------------------------------------------------
// Final GEMM, split-K x2: fp16 partial of cat @ Wlin^T (no bias/tanh).
// ---------------------------------------------------------------------------
__global__ __launch_bounds__(256, 3) void gemm_final_sk(
    const float* __restrict__ A0, const f16* __restrict__ A1,
    const f16* __restrict__ A2, const f16* __restrict__ B,
    f16* __restrict__ P0, f16* __restrict__ P1)
{
    __shared__ alignas(16) f16 As[128 * 32];
    __shared__ alignas(16) f16 Bs[128 * 32];
    const int t = threadIdx.x;
    const int lane = t & 63;
    const int w = t >> 6;
    const int kh = blockIdx.x >> 9;
    int bm, bn;
    swz_map(blockIdx.x & 511, 8, 64, bm, bn);
    const size_t m0 = (size_t)bm * 128;
    const size_t n0 = (size_t)bn * 128;
    const int wrow = (w >> 1) * 64;
    const int wcol = (w & 1) * 64;
    const int kBeg = kh * 1536;
    f16* __restrict__ P = kh ? P1 : P0;

    f32x4 acc[4][4] = {};

    for (int k0 = kBeg; k0 < kBeg + 1536; k0 += 32) {
        const int kl = k0 & 1023;
        __syncthreads();
        if (k0 < 1024) {
#pragma unroll
            for (int p = 0; p < 4; ++p) {
                const int idx = p * 256 + t;
                const int row = idx >> 3;
                const int col4 = (idx & 7) << 2;
                const f32x4 v = *(const f32x4*)&A0[(m0 + row) * 1024 + kl + col4];
                f16x4 h;
#pragma unroll
                for (int j = 0; j < 4; ++j) h[j] = (f16)v[j];
                *(f16x4*)&As[idx * 4] = h;
            }
        } else {
            const f16* Aseg = (k0 < 2048) ? A1 : A2;
#pragma unroll
            for (int i = 0; i < 2; ++i) {
                const int c = i * 256 + t;
                const int row = c >> 2;
                const int col = (c & 3) << 3;
                const int loff = (i * 256 + w * 64) * 8;
                gload_lds16(Aseg + (m0 + row) * (size_t)1024 + kl + col, &As[loff]);
            }
        }
#pragma unroll
        for (int i = 0; i < 2; ++i) {
            const int c = i * 256 + t;
            const int row = c >> 2;
            const int col = (c & 3) << 3;
            const int loff = (i * 256 + w * 64) * 8;
            gload_lds16(B + (n0 + row) * (size_t)3072 + k0 + col, &Bs[loff]);
        }
        __syncthreads();
        const int fr = lane & 15;
        const int fk = (lane >> 4) << 3;
        f16x8 a[4], b[4];
#pragma unroll
        for (int x = 0; x < 4; ++x) {
            a[x] = *(const f16x8*)&As[(wrow + x * 16 + fr) * 32 + fk];
            b[x] = *(const f16x8*)&Bs[(wcol + x * 16 + fr) * 32 + fk];
        }
#pragma unroll
        for (int mi = 0; mi < 4; ++mi)
#pragma unroll
            for (int ni = 0; ni < 4; ++ni)
                acc[mi][ni] = __builtin_amdgcn_mfma_f32_16x16x32_f16(a[mi], b[ni], acc[mi][ni], 0, 0, 0);
    }

    const int fr = lane & 15;
    const int fq = lane >> 4;
#pragma unroll
    for (int mi = 0; mi < 4; ++mi)
#pragma unroll
        for (int ni = 0; ni < 4; ++ni)
#pragma unroll
            for (int r = 0; r < 4; ++r) {
                const size_t row = m0 + wrow + mi * 16 + fq * 4 + r;
                const size_t col = n0 + wcol + ni * 16 + fr;
                P[row * 1024 + col] = (f16)acc[mi][ni][r];
            }
}

// ---------------------------------------------------------------------------
// Reduce / small kernels
// ---------------------------------------------------------------------------
__global__ __launch_bounds__(256) void reduce_add_f16(
    const f16* __restrict__ p0, const f16* __restrict__ p1,
    f16* __restrict__ out, int n8)
{
    for (int i = blockIdx.x * 256 + threadIdx.x; i < n8; i += gridDim.x * 256) {
        const f16x8 a = *(const f16x8*)&p0[(size_t)i * 8];
        const f16x8 b = *(const f16x8*)&p1[(size_t)i * 8];
        f16x8 o;
#pragma unroll
        for (int j = 0; j < 8; ++j) o[j] = (f16)((float)a[j] + (float)b[j]);
        *(f16x8*)&out[(size_t)i * 8] = o;
    }
}

__global__ __launch_bounds__(256) void reduce_tanh_f32(
    const f16* __restrict__ p0, const f16* __restrict__ p1,
    const float* __restrict__ bias, float* __restrict__ out, int n4)
{
    for (int i = blockIdx.x * 256 + threadIdx.x; i < n4; i += gridDim.x * 256) {
        const size_t e = (size_t)i * 4;
        const f16x4 a = *(const f16x4*)&p0[e];
        const f16x4 b = *(const f16x4*)&p1[e];
        f32x4 o;
#pragma unroll
        for (int j = 0; j < 4; ++j)
            o[j] = tanhf((float)a[j] + (float)b[j] + bias[(e + j) & 1023]);
        *(f32x4*)&out[e] = o;
    }
}

__global__ __launch_bounds__(256) void zero_f32(float* __restrict__ p, int n) {
    const int i = blockIdx.x * 256 + threadIdx.x;
    if (i < n) p[i] = 0.f;
}

__global__ __launch_bounds__(256) void inv_f32(float* __restrict__ p, int n) {
    const int i = blockIdx.x * 256 + threadIdx.x;
    if (i < n) p[i] = 1.f / p[i];
}

__global__ __launch_bounds__(256) void split_f32_f16(
    const float* __restrict__ X, f16* __restrict__ hi, f16* __restrict__ lo)
{
    const size_t i = ((size_t)blockIdx.x * 256 + threadIdx.x) * 4;
    const f32x4 v = *(const f32x4*)&X[i];
    f16x4 h, l;
#pragma unroll
    for (int j = 0; j < 4; ++j) {
        h[j] = (f16)v[j];
        l[j] = (f16)(v[j] - (float)h[j]);
    }
    *(f16x4*)&hi[i] = h;
    *(f16x4*)&lo[i] = l;
}

// ---------------------------------------------------------------------------
// Transpose X[N,H] f32 -> Xt[H,N] bf16 (64x64 tiles via LDS)
// ---------------------------------------------------------------------------
__global__ __launch_bounds__(256) void transpose_f32_to_bf16(
    const float* __restrict__ X, unsigned short* __restrict__ Xt, int N, int H)
{
    __shared__ float tile[64][65];
    const int n0 = blockIdx.x * 64;
    const int h0 = blockIdx.y * 64;
    const int tx = threadIdx.x & 15;
    const int ty = threadIdx.x >> 4;
#pragma unroll
    for (int i = 0; i < 4; ++i) {
        const int r = ty + i * 16;
        const f32x4 vv = *(const f32x4*)&X[(size_t)(n0 + r) * H + h0 + tx * 4];
        tile[r][tx * 4 + 0] = vv[0];
        tile[r][tx * 4 + 1] = vv[1];
        tile[r][tx * 4 + 2] = vv[2];
        tile[r][tx * 4 + 3] = vv[3];
    }
    __syncthreads();
#pragma unroll
    for (int i = 0; i < 4; ++i) {
        const int hh = ty + i * 16;
        u16x4 o;
        o[0] = f32_to_bf16(tile[tx * 4 + 0][hh]);
        o[1] = f32_to_bf16(tile[tx * 4 + 1][hh]);
        o[2] = f32_to_bf16(tile[tx * 4 + 2][hh]);
        o[3] = f32_to_bf16(tile[tx * 4 + 3][hh]);
        *(u16x4*)&Xt[(size_t)(h0 + hh) * N + n0 + tx * 4] = o;
    }
}

__global__ __launch_bounds__(256) void conv_f32_f16(
    const float* __restrict__ X, f16* __restrict__ Y)
{
    const size_t i = ((size_t)blockIdx.x * 256 + threadIdx.x) * 4;
    const f32x4 v = *(const f32x4*)&X[i];
    f16x4 h;
#pragma unroll
    for (int j = 0; j < 4; ++j) h[j] = (f16)v[j];
    *(f16x4*)&Y[i] = h;
}

// ---------------------------------------------------------------------------
extern "C" void kernel_launch(void* const* d_in, const int* in_sizes, int n_in,
                              void* d_out, int out_size, void* d_ws, size_t ws_size,
                              hipStream_t stream)
{
    (void)in_sizes; (void)n_in; (void)out_size;
    constexpr int Ns = 8192, Ne = 4096, M = 8192, H = 1024, K3 = 3072, AO = 1024;

    const float* Xss  = (const float*)d_in[0];
    const float* Xes  = (const float*)d_in[1];
    const float* Att  = (const float*)d_in[2];
    const float* Wss  = (const float*)d_in[3];
    const float* bss  = (const float*)d_in[4];
    const float* Wes  = (const float*)d_in[5];
    const float* bes  = (const float*)d_in[6];
    const float* Wlin = (const float*)d_in[7];
    const float* blin = (const float*)d_in[8];
    float* Out = (float*)d_out;

    // ---- workspace layout (~249.7 MB) ----
    char* base = (char*)d_ws;
    size_t off = 0;
    auto carve = [&](size_t bytes) {
        char* r = base + off;
        off = (off + bytes + 255) & ~(size_t)255;
        return r;
    };

    f16* Wl16            = (f16*)carve((size_t)AO * K3 * 2);            //   6.3 MB
    unsigned short* Vtss = (unsigned short*)carve((size_t)H * Ns * 2);  //  16.8 MB
    unsigned short* Vtes = (unsigned short*)carve((size_t)H * Ne * 2);  //   8.4 MB
    char* PesRg          = carve((size_t)2 * Ne * H * 2);               //  16.8 MB (Pes hi/lo -> Att_hi)
    char* PssRg          = carve((size_t)2 * Ns * H * 2);               //  33.6 MB (Pss hi/lo -> ctx-ss partials)
    char* E              = carve((size_t)M * Ns * 2);                   // 134.2 MB
    char* CtxssRg        = carve((size_t)M * H * 2);                    //  16.8 MB (Att_lo -> Ctxss)
    f16* Ctxes           = (f16*)carve((size_t)M * H * 2);              //  16.8 MB
    float* sum_ss        = (float*)carve((size_t)M * 4);
    float* sum_es        = (float*)carve((size_t)M * 4);
    if (off > ws_size) return;  // ws too small: fail loudly

    // Aliases into E: [0,67.1M) Ses | [67.1,83.9M) AhE | [83.9,100.7M) AlE
    //                 | [100.7,134.2M) es ctx partials. Then all of E = Sss,
    //                 then E = final partials. Liveness per launch order.
    f16* Pes_hi = (f16*)PesRg;
    f16* Pes_lo = Pes_hi + (size_t)Ne * H;
    f16* Att_hi = (f16*)PesRg;                         // after score-es
    f16* Att_lo = (f16*)CtxssRg;                       // until score-ss done
    f16* Pss_hi = (f16*)PssRg;
    f16* Pss_lo = Pss_hi + (size_t)Ns * H;
    unsigned short* Ses = (unsigned short*)E;          // [M, Ne]
    unsigned short* Sss = (unsigned short*)E;          // [M, Ns]
    f16* AhE   = (f16*)(E + (size_t)M * Ne * 2);       // es-phase Att hi
    f16* AlE   = AhE + (size_t)M * H;                  // es-phase Att lo
    f16* esP0  = (f16*)(E + (size_t)M * Ne * 2 + (size_t)2 * M * H * 2);
    f16* esP1  = esP0 + (size_t)M * H;                 // ends exactly at E end
    f16* ssP0  = (f16*)PssRg;                          // ss ctx partials (Pss dead)
    f16* ssP1  = ssP0 + (size_t)M * H;
    f16* Ctxss = (f16*)CtxssRg;
    f16* fnP0  = (f16*)E;                              // final partials (E dead)
    f16* fnP1  = fnP0 + (size_t)M * AO;

    const int n8 = (M * H) / 8;
    const int n4 = (M * AO) / 4;

    // ---- stage 0: conversions + sum init ----
    conv_f32_f16<<<(AO * K3) / 1024, 256, 0, stream>>>(Wlin, Wl16);
    transpose_f32_to_bf16<<<dim3(Ns / 64, H / 64), 256, 0, stream>>>(Xss, Vtss, Ns, H);
    transpose_f32_to_bf16<<<dim3(Ne / 64, H / 64), 256, 0, stream>>>(Xes, Vtes, Ne, H);
    zero_f32<<<(2 * M) / 256, 256, 0, stream>>>(sum_ss, 2 * M);  // sum_ss+sum_es contiguous

    // ---- stage 1: projections ----
    gemm_proj<<<dim3(H / 128, Ns / 128), 256, 0, stream>>>(Xss, Wss, bss, H, Pss_hi, Pss_lo);
    gemm_proj<<<dim3(H / 128, Ne / 128), 256, 0, stream>>>(Xes, Wes, bes, H, Pes_hi, Pes_lo);

    // ---- es phase: split Att into E tail -> score(4op, n-swz, 256x128) -> ctx ----
    split_f32_f16<<<(M * H) / 1024, 256, 0, stream>>>(Att, AhE, AlE);
    gemm_score_4op<<<32 * (M / 256), 512, 0, stream>>>(
        AhE, AlE, Pes_hi, Pes_lo, 32, Ses, sum_es);
    // re-split Att into persistent homes (Pes dead now; CtxssRg unwritten)
    split_f32_f16<<<(M * H) / 1024, 256, 0, stream>>>(Att, Att_hi, Att_lo);
    inv_f32<<<M / 256, 256, 0, stream>>>(sum_es, M);
    gemm_ctx_sk<<<1024, 256, 0, stream>>>(Ses, Vtes, sum_es, Ne, Ne / 2, esP0, esP1);
    reduce_add_f16<<<1024, 256, 0, stream>>>(esP0, esP1, Ctxes, n8);

    // ---- ss phase: score(4op, n-swz, 256x128) -> ctx ----
    gemm_score_4op<<<64 * (M / 256), 512, 0, stream>>>(
        Att_hi, Att_lo, Pss_hi, Pss_lo, 64, Sss, sum_ss);
    inv_f32<<<M / 256, 256, 0, stream>>>(sum_ss, M);
    gemm_ctx_sk<<<1024, 256, 0, stream>>>(Sss, Vtss, sum_ss, Ns, Ns / 2, ssP0, ssP1);
    reduce_add_f16<<<1024, 256, 0, stream>>>(ssP0, ssP1, Ctxss, n8);

    // ---- stage 3: out = tanh([att, ctx_ss, ctx_es] @ Wlin^T + b) ----
    gemm_final_sk<<<1024, 256, 0, stream>>>(Att, Ctxss, Ctxes, Wl16, fnP0, fnP1);
    reduce_tanh_f32<<<1024, 256, 0, stream>>>(fnP0, fnP1, blin, Out, n4);
}

// Round 15
// 1065.031 us; speedup vs baseline: 5.4697x; 1.2349x over previous
//
#include <hip/hip_runtime.h>
#include <hip/hip_fp16.h>
#include <stdint.h>

typedef _Float16 f16;
typedef _Float16 f16x8 __attribute__((ext_vector_type(8)));
typedef _Float16 f16x4 __attribute__((ext_vector_type(4)));
typedef float f32x4 __attribute__((ext_vector_type(4)));
typedef short s16x8 __attribute__((ext_vector_type(8)));          // 8 bf16
typedef unsigned short u16x8 __attribute__((ext_vector_type(8)));
typedef unsigned short u16x4 __attribute__((ext_vector_type(4)));

#define DEV __device__ __forceinline__

DEV void gload_lds16(const void* g, void* l) {
    __builtin_amdgcn_global_load_lds(
        (const __attribute__((address_space(1))) void*)g,
        (__attribute__((address_space(3))) void*)l, 16, 0, 0);
}

DEV unsigned short f32_to_bf16(float x) {
    union { float f; unsigned int u; } c; c.f = x;
    unsigned int r = (c.u + 0x7FFFu + ((c.u >> 16) & 1u)) >> 16;
    return (unsigned short)r;
}

// XCD panel-grouped swizzle (m-panels pinned per XCD): used by ctx/final.
DEV void swz_map(int bid, int nx, int ny, int& bm, int& bn) {
    const int xcd = bid & 7;
    const int j = bid >> 3;
    const int py = ny >> 3;
    bm = xcd * py + j / nx;
    bn = j % nx;
}

// XCD n-grouped swizzle (n-tiles pinned per XCD, m fastest): for score.
DEV void swz_map_n(int bid, int nx, int& bm, int& bn) {
    const int xcd = bid & 7;
    const int j = bid >> 3;
    const int px = nx >> 3;
    bn = xcd * px + (j % px);
    bm = j / px;
}

// Shared score epilogue: e = exp(acc-150) -> bf16 store + fused row-sum
// (shfl over fr-group + one atomicAdd per row per wave).
DEV void score_epilogue(f32x4 (&acc)[4][4], size_t m0, size_t n0,
                        int wrow, int wcol, int lane, int ldc,
                        unsigned short* __restrict__ Sp,
                        float* __restrict__ rsum)
{
    const int fr = lane & 15;
    const int fq = lane >> 4;
#pragma unroll
    for (int mi = 0; mi < 4; ++mi)
#pragma unroll
        for (int r = 0; r < 4; ++r) {
            const size_t row = m0 + wrow + mi * 16 + fq * 4 + r;
            float rowacc = 0.f;
#pragma unroll
            for (int ni = 0; ni < 4; ++ni) {
                const size_t col = n0 + wcol + ni * 16 + fr;
                const float e = __expf(acc[mi][ni][r] - 150.f);
                Sp[row * (size_t)ldc + col] = f32_to_bf16(e);
                rowacc += e;
            }
#pragma unroll
            for (int m = 1; m < 16; m <<= 1) rowacc += __shfl_xor(rowacc, m);
            if (fr == 0) atomicAdd(&rsum[row], rowacc);
        }
}

// ---------------------------------------------------------------------------
// Score GEMM (4-operand fp16, 256x128 tile, 8 waves/512 thr, XCD n-grouped
// 1-D grid = nx * M/256): S' = bf16(exp((Ah+Al)@(Bh+Bl)^T - 150)), K=1024,
// drop lo*lo. Single-buffered 2-barrier loop; (512,4) is the max safe
// occupancy bound: (512,6) forces VGPR<=85 -> accumulator spill (r13,
// 9.8GB scratch traffic, 5.5x slower). Fused row-sum atomics. ldc = nx*128.
// ---------------------------------------------------------------------------
__global__ __launch_bounds__(512, 4) void gemm_score_4op(
    const f16* __restrict__ Ahi, const f16* __restrict__ Alo,
    const f16* __restrict__ Bhi, const f16* __restrict__ Blo,
    int nx, unsigned short* __restrict__ Sp, float* __restrict__ rsum)
{
    __shared__ alignas(16) f16 As_hi[256 * 32];
    __shared__ alignas(16) f16 As_lo[256 * 32];
    __shared__ alignas(16) f16 Bs_hi[128 * 32];
    __shared__ alignas(16) f16 Bs_lo[128 * 32];
    const int t = threadIdx.x;
    const int lane = t & 63;
    const int w = t >> 6;                 // 0..7
    int bm, bn;
    swz_map_n(blockIdx.x, nx, bm, bn);
    const size_t m0 = (size_t)bm * 256;
    const size_t n0 = (size_t)bn * 128;
    const int ldc = nx * 128;
    const int wrow = (w >> 1) * 64;       // 0,64,128,192
    const int wcol = (w & 1) * 64;        // 0,64
    const int fr = lane & 15;
    const int fk = (lane >> 4) << 3;

    const int cA0 = t, cA1 = 512 + t;     // A: 1024 slots (256 rows)
    const int rA0 = cA0 >> 2, qA0 = (cA0 & 3) << 3;
    const int rA1 = cA1 >> 2, qA1 = (cA1 & 3) << 3;
    const int loffA0 = (0 * 512 + w * 64) * 8;
    const int loffA1 = (1 * 512 + w * 64) * 8;
    const int rB = t >> 2, qB = (t & 3) << 3;   // B: 512 slots (128 rows)
    const int loffB = (w * 64) * 8;
    const size_t gA0 = (m0 + rA0) * 1024 + qA0;
    const size_t gA1 = (m0 + rA1) * 1024 + qA1;
    const size_t gB  = (n0 + rB) * 1024 + qB;

    f32x4 acc[4][4] = {};

    for (int k0 = 0; k0 < 1024; k0 += 32) {
        __syncthreads();
        gload_lds16(Ahi + gA0 + k0, &As_hi[loffA0]);
        gload_lds16(Ahi + gA1 + k0, &As_hi[loffA1]);
        gload_lds16(Alo + gA0 + k0, &As_lo[loffA0]);
        gload_lds16(Alo + gA1 + k0, &As_lo[loffA1]);
        gload_lds16(Bhi + gB + k0, &Bs_hi[loffB]);
        gload_lds16(Blo + gB + k0, &Bs_lo[loffB]);
        __syncthreads();
        f16x8 ah[4], al[4], bh[4], bl[4];
#pragma unroll
        for (int x = 0; x < 4; ++x) {
            const int ea = (wrow + x * 16 + fr) * 32 + fk;
            const int eb = (wcol + x * 16 + fr) * 32 + fk;
            ah[x] = *(const f16x8*)&As_hi[ea];
            al[x] = *(const f16x8*)&As_lo[ea];
            bh[x] = *(const f16x8*)&Bs_hi[eb];
            bl[x] = *(const f16x8*)&Bs_lo[eb];
        }
#pragma unroll
        for (int mi = 0; mi < 4; ++mi)
#pragma unroll
            for (int ni = 0; ni < 4; ++ni) {
                acc[mi][ni] = __builtin_amdgcn_mfma_f32_16x16x32_f16(ah[mi], bh[ni], acc[mi][ni], 0, 0, 0);
                acc[mi][ni] = __builtin_amdgcn_mfma_f32_16x16x32_f16(al[mi], bh[ni], acc[mi][ni], 0, 0, 0);
                acc[mi][ni] = __builtin_amdgcn_mfma_f32_16x16x32_f16(ah[mi], bl[ni], acc[mi][ni], 0, 0, 0);
            }
    }

    score_epilogue(acc, m0, n0, wrow, wcol, lane, ldc, Sp, rsum);
}

// ---------------------------------------------------------------------------
// Projection GEMM: P(hi,lo) = (A_f32 split) @ (B_f32 split)^T + bias, K=1024.
// (256,2): deeper bounds risk spill (r14 regression).
// ---------------------------------------------------------------------------
__global__ __launch_bounds__(256, 2) void gemm_proj(
    const float* __restrict__ A, const float* __restrict__ B,
    const float* __restrict__ bias, int ldc,
    f16* __restrict__ Phi, f16* __restrict__ Plo)
{
    __shared__ alignas(16) f16 As_hi[128 * 32];
    __shared__ alignas(16) f16 As_lo[128 * 32];
    __shared__ alignas(16) f16 Bs_hi[128 * 32];
    __shared__ alignas(16) f16 Bs_lo[128 * 32];
    const int t = threadIdx.x;
    const int lane = t & 63;
    const int w = t >> 6;
    const size_t m0 = (size_t)blockIdx.y * 128;
    const size_t n0 = (size_t)blockIdx.x * 128;
    const int wrow = (w >> 1) * 64;
    const int wcol = (w & 1) * 64;

    f32x4 acc[4][4] = {};

    for (int k0 = 0; k0 < 1024; k0 += 32) {
        __syncthreads();
#pragma unroll
        for (int p = 0; p < 4; ++p) {
            const int idx = p * 256 + t;
            const int row = idx >> 3;
            const int col4 = (idx & 7) << 2;
            const f32x4 va = *(const f32x4*)&A[(m0 + row) * 1024 + k0 + col4];
            const f32x4 vb = *(const f32x4*)&B[(n0 + row) * 1024 + k0 + col4];
            f16x4 ha, la, hb, lb;
#pragma unroll
            for (int j = 0; j < 4; ++j) {
                ha[j] = (f16)va[j];
                la[j] = (f16)(va[j] - (float)ha[j]);
                hb[j] = (f16)vb[j];
                lb[j] = (f16)(vb[j] - (float)hb[j]);
            }
            *(f16x4*)&As_hi[idx * 4] = ha;
            *(f16x4*)&As_lo[idx * 4] = la;
            *(f16x4*)&Bs_hi[idx * 4] = hb;
            *(f16x4*)&Bs_lo[idx * 4] = lb;
        }
        __syncthreads();
        const int fr = lane & 15;
        const int fk = (lane >> 4) << 3;
        f16x8 ah[4], al[4], bh[4], bl[4];
#pragma unroll
        for (int x = 0; x < 4; ++x) {
            ah[x] = *(const f16x8*)&As_hi[(wrow + x * 16 + fr) * 32 + fk];
            al[x] = *(const f16x8*)&As_lo[(wrow + x * 16 + fr) * 32 + fk];
            bh[x] = *(const f16x8*)&Bs_hi[(wcol + x * 16 + fr) * 32 + fk];
            bl[x] = *(const f16x8*)&Bs_lo[(wcol + x * 16 + fr) * 32 + fk];
        }
#pragma unroll
        for (int mi = 0; mi < 4; ++mi)
#pragma unroll
            for (int ni = 0; ni < 4; ++ni) {
                acc[mi][ni] = __builtin_amdgcn_mfma_f32_16x16x32_f16(ah[mi], bh[ni], acc[mi][ni], 0, 0, 0);
                acc[mi][ni] = __builtin_amdgcn_mfma_f32_16x16x32_f16(al[mi], bh[ni], acc[mi][ni], 0, 0, 0);
                acc[mi][ni] = __builtin_amdgcn_mfma_f32_16x16x32_f16(ah[mi], bl[ni], acc[mi][ni], 0, 0, 0);
            }
    }

    const int fr = lane & 15;
    const int fq = lane >> 4;
#pragma unroll
    for (int mi = 0; mi < 4; ++mi)
#pragma unroll
        for (int ni = 0; ni < 4; ++ni)
#pragma unroll
            for (int r = 0; r < 4; ++r) {
                const size_t row = m0 + wrow + mi * 16 + fq * 4 + r;
                const size_t col = n0 + wcol + ni * 16 + fr;
                float v = acc[mi][ni][r] + bias[col];
                const f16 h = (f16)v;
                Phi[row * (size_t)ldc + col] = h;
                Plo[row * (size_t)ldc + col] = (f16)(v - (float)h);
            }
}

// ---------------------------------------------------------------------------
// bf16 ctx GEMM with split-K x2: grid = 1024 (2 K-halves x 512 XCD-swz).
// Partial(fp16) = (A[:, kh*K2..) @ B[:, same)^T) * inv_sum[row].
// (256,4): measured best (r12); (256,5) was part of the r14 regression.
// ---------------------------------------------------------------------------
__global__ __launch_bounds__(256, 4) void gemm_ctx_sk(
    const unsigned short* __restrict__ A, const unsigned short* __restrict__ B,
    const float* __restrict__ isum, int ldk, int K2,
    f16* __restrict__ P0, f16* __restrict__ P1)
{
    __shared__ alignas(16) unsigned short LA[2][128 * 32];
    __shared__ alignas(16) unsigned short LB[2][128 * 32];
    const int t = threadIdx.x;
    const int lane = t & 63;
    const int w = t >> 6;
    const int kh = blockIdx.x >> 9;
    int bm, bn;
    swz_map(blockIdx.x & 511, 8, 64, bm, bn);
    const size_t m0 = (size_t)bm * 128;
    const size_t n0 = (size_t)bn * 128;
    const size_t koff = (size_t)kh * K2;
    const int wrow = (w >> 1) * 64;
    const int wcol = (w & 1) * 64;
    const int fr = lane & 15;
    const int bslot = lane >> 4;
    f16* __restrict__ P = kh ? P1 : P0;

    const int s0 = t, s1 = 256 + t;
    const int r0 = s0 >> 2, c0 = s0 & 3;
    const int r1 = s1 >> 2, c1 = s1 & 3;
    const size_t ga0 = (m0 + r0) * (size_t)ldk + koff + ((c0 ^ (r0 & 3)) << 3);
    const size_t ga1 = (m0 + r1) * (size_t)ldk + koff + ((c1 ^ (r1 & 3)) << 3);
    const size_t gb0 = (n0 + r0) * (size_t)ldk + koff + ((c0 ^ (r0 & 3)) << 3);
    const size_t gb1 = (n0 + r1) * (size_t)ldk + koff + ((c1 ^ (r1 & 3)) << 3);

    f32x4 acc[4][4] = {};

    auto stage = [&](int kt, int b) {
        const int k0 = kt << 5;
        gload_lds16(A + ga0 + k0, &LA[b][(size_t)s0 * 8]);
        gload_lds16(A + ga1 + k0, &LA[b][(size_t)s1 * 8]);
        gload_lds16(B + gb0 + k0, &LB[b][(size_t)s0 * 8]);
        gload_lds16(B + gb1 + k0, &LB[b][(size_t)s1 * 8]);
    };

    auto compute = [&](int b) {
        s16x8 a[4], bb[4];
#pragma unroll
        for (int x = 0; x < 4; ++x) {
            const int ra = wrow + x * 16 + fr;
            const int rb = wcol + x * 16 + fr;
            a[x]  = *(const s16x8*)&LA[b][ra * 32 + ((bslot ^ (ra & 3)) << 3)];
            bb[x] = *(const s16x8*)&LB[b][rb * 32 + ((bslot ^ (rb & 3)) << 3)];
        }
#pragma unroll
        for (int mi = 0; mi < 4; ++mi)
#pragma unroll
            for (int ni = 0; ni < 4; ++ni)
                acc[mi][ni] = __builtin_amdgcn_mfma_f32_16x16x32_bf16(a[mi], bb[ni], acc[mi][ni], 0, 0, 0);
    };

    const int NT = K2 >> 5;
    stage(0, 0);
#pragma unroll 1
    for (int kt = 0; kt < NT; kt += 2) {
        __syncthreads();
        if (kt + 1 < NT) stage(kt + 1, 1);
        __builtin_amdgcn_s_setprio(1);
        compute(0);
        __builtin_amdgcn_s_setprio(0);
        __syncthreads();
        if (kt + 2 < NT) stage(kt + 2, 0);
        __builtin_amdgcn_s_setprio(1);
        compute(1);
        __builtin_amdgcn_s_setprio(0);
    }

    const int fq = lane >> 4;
#pragma unroll
    for (int mi = 0; mi < 4; ++mi)
#pragma unroll
        for (int ni = 0; ni < 4; ++ni)
#pragma unroll
            for (int r = 0; r < 4; ++r) {
                const size_t row = m0 + wrow + mi * 16 + fq * 4 + r;
                const size_t col = n0 + wcol + ni * 16 + fr;
                P[row * 1024 + col] = (f16)(acc[mi][ni][r] * isum[row]);
            }
}

// ---------------------------------------------------------------------------
// Final GEMM, split-K x2: fp16 partial of cat @ Wlin^T (no bias/tanh).
// ---------------------------------------------------------------------------
__global__ __launch_bounds__(256, 2) void gemm_final_sk(
    const float* __restrict__ A0, const f16* __restrict__ A1,
    const f16* __restrict__ A2, const f16* __restrict__ B,
    f16* __restrict__ P0, f16* __restrict__ P1)
{
    __shared__ alignas(16) f16 As[128 * 32];
    __shared__ alignas(16) f16 Bs[128 * 32];
    const int t = threadIdx.x;
    const int lane = t & 63;
    const int w = t >> 6;
    const int kh = blockIdx.x >> 9;
    int bm, bn;
    swz_map(blockIdx.x & 511, 8, 64, bm, bn);
    const size_t m0 = (size_t)bm * 128;
    const size_t n0 = (size_t)bn * 128;
    const int wrow = (w >> 1) * 64;
    const int wcol = (w & 1) * 64;
    const int kBeg = kh * 1536;
    f16* __restrict__ P = kh ? P1 : P0;

    f32x4 acc[4][4] = {};

    for (int k0 = kBeg; k0 < kBeg + 1536; k0 += 32) {
        const int kl = k0 & 1023;
        __syncthreads();
        if (k0 < 1024) {
#pragma unroll
            for (int p = 0; p < 4; ++p) {
                const int idx = p * 256 + t;
                const int row = idx >> 3;
                const int col4 = (idx & 7) << 2;
                const f32x4 v = *(const f32x4*)&A0[(m0 + row) * 1024 + kl + col4];
                f16x4 h;
#pragma unroll
                for (int j = 0; j < 4; ++j) h[j] = (f16)v[j];
                *(f16x4*)&As[idx * 4] = h;
            }
        } else {
            const f16* Aseg = (k0 < 2048) ? A1 : A2;
#pragma unroll
            for (int i = 0; i < 2; ++i) {
                const int c = i * 256 + t;
                const int row = c >> 2;
                const int col = (c & 3) << 3;
                const int loff = (i * 256 + w * 64) * 8;
                gload_lds16(Aseg + (m0 + row) * (size_t)1024 + kl + col, &As[loff]);
            }
        }
#pragma unroll
        for (int i = 0; i < 2; ++i) {
            const int c = i * 256 + t;
            const int row = c >> 2;
            const int col = (c & 3) << 3;
            const int loff = (i * 256 + w * 64) * 8;
            gload_lds16(B + (n0 + row) * (size_t)3072 + k0 + col, &Bs[loff]);
        }
        __syncthreads();
        const int fr = lane & 15;
        const int fk = (lane >> 4) << 3;
        f16x8 a[4], b[4];
#pragma unroll
        for (int x = 0; x < 4; ++x) {
            a[x] = *(const f16x8*)&As[(wrow + x * 16 + fr) * 32 + fk];
            b[x] = *(const f16x8*)&Bs[(wcol + x * 16 + fr) * 32 + fk];
        }
#pragma unroll
        for (int mi = 0; mi < 4; ++mi)
#pragma unroll
            for (int ni = 0; ni < 4; ++ni)
                acc[mi][ni] = __builtin_amdgcn_mfma_f32_16x16x32_f16(a[mi], b[ni], acc[mi][ni], 0, 0, 0);
    }

    const int fr = lane & 15;
    const int fq = lane >> 4;
#pragma unroll
    for (int mi = 0; mi < 4; ++mi)
#pragma unroll
        for (int ni = 0; ni < 4; ++ni)
#pragma unroll
            for (int r = 0; r < 4; ++r) {
                const size_t row = m0 + wrow + mi * 16 + fq * 4 + r;
                const size_t col = n0 + wcol + ni * 16 + fr;
                P[row * 1024 + col] = (f16)acc[mi][ni][r];
            }
}

// ---------------------------------------------------------------------------
// Reduce / small kernels
// ---------------------------------------------------------------------------
__global__ __launch_bounds__(256) void reduce_add_f16(
    const f16* __restrict__ p0, const f16* __restrict__ p1,
    f16* __restrict__ out, int n8)
{
    for (int i = blockIdx.x * 256 + threadIdx.x; i < n8; i += gridDim.x * 256) {
        const f16x8 a = *(const f16x8*)&p0[(size_t)i * 8];
        const f16x8 b = *(const f16x8*)&p1[(size_t)i * 8];
        f16x8 o;
#pragma unroll
        for (int j = 0; j < 8; ++j) o[j] = (f16)((float)a[j] + (float)b[j]);
        *(f16x8*)&out[(size_t)i * 8] = o;
    }
}

__global__ __launch_bounds__(256) void reduce_tanh_f32(
    const f16* __restrict__ p0, const f16* __restrict__ p1,
    const float* __restrict__ bias, float* __restrict__ out, int n4)
{
    for (int i = blockIdx.x * 256 + threadIdx.x; i < n4; i += gridDim.x * 256) {
        const size_t e = (size_t)i * 4;
        const f16x4 a = *(const f16x4*)&p0[e];
        const f16x4 b = *(const f16x4*)&p1[e];
        f32x4 o;
#pragma unroll
        for (int j = 0; j < 4; ++j)
            o[j] = tanhf((float)a[j] + (float)b[j] + bias[(e + j) & 1023]);
        *(f32x4*)&out[e] = o;
    }
}

__global__ __launch_bounds__(256) void zero_f32(float* __restrict__ p, int n) {
    const int i = blockIdx.x * 256 + threadIdx.x;
    if (i < n) p[i] = 0.f;
}

__global__ __launch_bounds__(256) void inv_f32(float* __restrict__ p, int n) {
    const int i = blockIdx.x * 256 + threadIdx.x;
    if (i < n) p[i] = 1.f / p[i];
}

__global__ __launch_bounds__(256) void split_f32_f16(
    const float* __restrict__ X, f16* __restrict__ hi, f16* __restrict__ lo)
{
    const size_t i = ((size_t)blockIdx.x * 256 + threadIdx.x) * 4;
    const f32x4 v = *(const f32x4*)&X[i];
    f16x4 h, l;
#pragma unroll
    for (int j = 0; j < 4; ++j) {
        h[j] = (f16)v[j];
        l[j] = (f16)(v[j] - (float)h[j]);
    }
    *(f16x4*)&hi[i] = h;
    *(f16x4*)&lo[i] = l;
}

// ---------------------------------------------------------------------------
// Transpose X[N,H] f32 -> Xt[H,N] bf16 (64x64 tiles via LDS)
// ---------------------------------------------------------------------------
__global__ __launch_bounds__(256) void transpose_f32_to_bf16(
    const float* __restrict__ X, unsigned short* __restrict__ Xt, int N, int H)
{
    __shared__ float tile[64][65];
    const int n0 = blockIdx.x * 64;
    const int h0 = blockIdx.y * 64;
    const int tx = threadIdx.x & 15;
    const int ty = threadIdx.x >> 4;
#pragma unroll
    for (int i = 0; i < 4; ++i) {
        const int r = ty + i * 16;
        const f32x4 vv = *(const f32x4*)&X[(size_t)(n0 + r) * H + h0 + tx * 4];
        tile[r][tx * 4 + 0] = vv[0];
        tile[r][tx * 4 + 1] = vv[1];
        tile[r][tx * 4 + 2] = vv[2];
        tile[r][tx * 4 + 3] = vv[3];
    }
    __syncthreads();
#pragma unroll
    for (int i = 0; i < 4; ++i) {
        const int hh = ty + i * 16;
        u16x4 o;
        o[0] = f32_to_bf16(tile[tx * 4 + 0][hh]);
        o[1] = f32_to_bf16(tile[tx * 4 + 1][hh]);
        o[2] = f32_to_bf16(tile[tx * 4 + 2][hh]);
        o[3] = f32_to_bf16(tile[tx * 4 + 3][hh]);
        *(u16x4*)&Xt[(size_t)(h0 + hh) * N + n0 + tx * 4] = o;
    }
}

__global__ __launch_bounds__(256) void conv_f32_f16(
    const float* __restrict__ X, f16* __restrict__ Y)
{
    const size_t i = ((size_t)blockIdx.x * 256 + threadIdx.x) * 4;
    const f32x4 v = *(const f32x4*)&X[i];
    f16x4 h;
#pragma unroll
    for (int j = 0; j < 4; ++j) h[j] = (f16)v[j];
    *(f16x4*)&Y[i] = h;
}

// ---------------------------------------------------------------------------
extern "C" void kernel_launch(void* const* d_in, const int* in_sizes, int n_in,
                              void* d_out, int out_size, void* d_ws, size_t ws_size,
                              hipStream_t stream)
{
    (void)in_sizes; (void)n_in; (void)out_size;
    constexpr int Ns = 8192, Ne = 4096, M = 8192, H = 1024, K3 = 3072, AO = 1024;

    const float* Xss  = (const float*)d_in[0];
    const float* Xes  = (const float*)d_in[1];
    const float* Att  = (const float*)d_in[2];
    const float* Wss  = (const float*)d_in[3];
    const float* bss  = (const float*)d_in[4];
    const float* Wes  = (const float*)d_in[5];
    const float* bes  = (const float*)d_in[6];
    const float* Wlin = (const float*)d_in[7];
    const float* blin = (const float*)d_in[8];
    float* Out = (float*)d_out;

    // ---- workspace layout (~249.7 MB) ----
    char* base = (char*)d_ws;
    size_t off = 0;
    auto carve = [&](size_t bytes) {
        char* r = base + off;
        off = (off + bytes + 255) & ~(size_t)255;
        return r;
    };

    f16* Wl16            = (f16*)carve((size_t)AO * K3 * 2);            //   6.3 MB
    unsigned short* Vtss = (unsigned short*)carve((size_t)H * Ns * 2);  //  16.8 MB
    unsigned short* Vtes = (unsigned short*)carve((size_t)H * Ne * 2);  //   8.4 MB
    char* PesRg          = carve((size_t)2 * Ne * H * 2);               //  16.8 MB (Pes hi/lo -> Att_hi)
    char* PssRg          = carve((size_t)2 * Ns * H * 2);               //  33.6 MB (Pss hi/lo -> ctx-ss partials)
    char* E              = carve((size_t)M * Ns * 2);                   // 134.2 MB
    char* CtxssRg        = carve((size_t)M * H * 2);                    //  16.8 MB (Att_lo -> Ctxss)
    f16* Ctxes           = (f16*)carve((size_t)M * H * 2);              //  16.8 MB
    float* sum_ss        = (float*)carve((size_t)M * 4);
    float* sum_es        = (float*)carve((size_t)M * 4);
    if (off > ws_size) return;  // ws too small: fail loudly

    // Aliases into E: [0,67.1M) Ses | [67.1,83.9M) AhE | [83.9,100.7M) AlE
    //                 | [100.7,134.2M) es ctx partials. Then all of E = Sss,
    //                 then E = final partials. Liveness per launch order.
    f16* Pes_hi = (f16*)PesRg;
    f16* Pes_lo = Pes_hi + (size_t)Ne * H;
    f16* Att_hi = (f16*)PesRg;                         // after score-es
    f16* Att_lo = (f16*)CtxssRg;                       // until score-ss done
    f16* Pss_hi = (f16*)PssRg;
    f16* Pss_lo = Pss_hi + (size_t)Ns * H;
    unsigned short* Ses = (unsigned short*)E;          // [M, Ne]
    unsigned short* Sss = (unsigned short*)E;          // [M, Ns]
    f16* AhE   = (f16*)(E + (size_t)M * Ne * 2);       // es-phase Att hi
    f16* AlE   = AhE + (size_t)M * H;                  // es-phase Att lo
    f16* esP0  = (f16*)(E + (size_t)M * Ne * 2 + (size_t)2 * M * H * 2);
    f16* esP1  = esP0 + (size_t)M * H;                 // ends exactly at E end
    f16* ssP0  = (f16*)PssRg;                          // ss ctx partials (Pss dead)
    f16* ssP1  = ssP0 + (size_t)M * H;
    f16* Ctxss = (f16*)CtxssRg;
    f16* fnP0  = (f16*)E;                              // final partials (E dead)
    f16* fnP1  = fnP0 + (size_t)M * AO;

    const int n8 = (M * H) / 8;
    const int n4 = (M * AO) / 4;

    // ---- stage 0: conversions + sum init ----
    conv_f32_f16<<<(AO * K3) / 1024, 256, 0, stream>>>(Wlin, Wl16);
    transpose_f32_to_bf16<<<dim3(Ns / 64, H / 64), 256, 0, stream>>>(Xss, Vtss, Ns, H);
    transpose_f32_to_bf16<<<dim3(Ne / 64, H / 64), 256, 0, stream>>>(Xes, Vtes, Ne, H);
    zero_f32<<<(2 * M) / 256, 256, 0, stream>>>(sum_ss, 2 * M);  // sum_ss+sum_es contiguous

    // ---- stage 1: projections ----
    gemm_proj<<<dim3(H / 128, Ns / 128), 256, 0, stream>>>(Xss, Wss, bss, H, Pss_hi, Pss_lo);
    gemm_proj<<<dim3(H / 128, Ne / 128), 256, 0, stream>>>(Xes, Wes, bes, H, Pes_hi, Pes_lo);

    // ---- es phase: split Att into E tail -> score(4op, n-swz, 256x128) -> ctx ----
    split_f32_f16<<<(M * H) / 1024, 256, 0, stream>>>(Att, AhE, AlE);
    gemm_score_4op<<<32 * (M / 256), 512, 0, stream>>>(
        AhE, AlE, Pes_hi, Pes_lo, 32, Ses, sum_es);
    // re-split Att into persistent homes (Pes dead now; CtxssRg unwritten)
    split_f32_f16<<<(M * H) / 1024, 256, 0, stream>>>(Att, Att_hi, Att_lo);
    inv_f32<<<M / 256, 256, 0, stream>>>(sum_es, M);
    gemm_ctx_sk<<<1024, 256, 0, stream>>>(Ses, Vtes, sum_es, Ne, Ne / 2, esP0, esP1);
    reduce_add_f16<<<1024, 256, 0, stream>>>(esP0, esP1, Ctxes, n8);

    // ---- ss phase: score(4op, n-swz, 256x128) -> ctx ----
    gemm_score_4op<<<64 * (M / 256), 512, 0, stream>>>(
        Att_hi, Att_lo, Pss_hi, Pss_lo, 64, Sss, sum_ss);
    inv_f32<<<M / 256, 256, 0, stream>>>(sum_ss, M);
    gemm_ctx_sk<<<1024, 256, 0, stream>>>(Sss, Vtss, sum_ss, Ns, Ns / 2, ssP0, ssP1);
    reduce_add_f16<<<1024, 256, 0, stream>>>(ssP0, ssP1, Ctxss, n8);

    // ---- stage 3: out = tanh([att, ctx_ss, ctx_es] @ Wlin^T + b) ----
    gemm_final_sk<<<1024, 256, 0, stream>>>(Att, Ctxss, Ctxes, Wl16, fnP0, fnP1);
    reduce_tanh_f32<<<1024, 256, 0, stream>>>(fnP0, fnP1, blin, Out, n4);
}